// Round 2
// baseline (85.018 us; speedup 1.0000x reference)
//
#include <hip/hip_runtime.h>
#include <hip/hip_bf16.h>

#define B_ 8
#define D_ 64
#define N_ 4096
#define M_ 4096
#define B3N (B_*3*N_)

// exp(s/8) = exp2(s * 0.125 * log2(e))
#define SCALE2 0.18033688011112042f

typedef short bf16x8 __attribute__((ext_vector_type(8)));
typedef float f32x4 __attribute__((ext_vector_type(4)));

#define LDSTRIDE 66   // shorts per d-row (64 + 2 pad) -> conflict-free by construction

__device__ __forceinline__ unsigned short f2bf(float f) {
    union { __hip_bfloat16 h; unsigned short u; } cv;
    cv.h = __float2bfloat16(f);
    return cv.u;
}

__device__ __forceinline__ uint2 pack4(float4 v) {
    uint2 r;
    r.x = (unsigned)f2bf(v.x) | ((unsigned)f2bf(v.y) << 16);
    r.y = (unsigned)f2bf(v.z) | ((unsigned)f2bf(v.w) << 16);
    return r;
}

// One wave per block. n-tile = 64 (Q fragments resident in VGPRs for whole m-loop).
// Computes S^T tiles (m rows, n cols) via mfma(K_frag, Q_frag) so the softmax
// m-reduction is lane-local; per-lane online accumulation of denom + 3 numerators.
// Fragment loads: plain ds_read_u16 from [d][p] LDS (stride 66 shorts) — no tr-read.
template<int S, bool DIRECT>
__global__ __launch_bounds__(64)
void attn_kernel(const float* __restrict__ qe, const float* __restrict__ ke,
                 const float* __restrict__ tgt, float* __restrict__ ws,
                 float* __restrict__ out)
{
    __shared__ unsigned short qs[64 * LDSTRIDE];  // Q tile: [d][p]
    __shared__ unsigned short ks[64 * LDSTRIDE];  // K tile: [d][p]
    __shared__ __align__(16) float ts[3 * 64];    // tgt tile f32

    const int t  = threadIdx.x;
    const int b  = blockIdx.z;
    const int n0 = blockIdx.x * 64;
    const int slice = blockIdx.y;
    const int mchunk = M_ / S;
    const int mbase  = slice * mchunk;

    const int tq = t & 15;
    const int dg = t >> 4;   // staging d sub-row
    const int g  = dg;       // mfma lane group (l>>4)
    const int lm = tq;       // mfma lane-in-group (l&15)

    // ---- stage Q tile: 64d x 64n, f32 -> bf16, [d][p] stride 66 ----
    {
        const float* src = qe + (size_t)b * D_ * N_ + n0 + 4*tq;
        #pragma unroll
        for (int i = 0; i < 16; ++i) {
            int d = 4*i + dg;
            float4 v = *(const float4*)(src + (size_t)d * N_);
            uint2 w = pack4(v);
            unsigned* p32 = (unsigned*)&qs[d*LDSTRIDE + 4*tq];
            p32[0] = w.x; p32[1] = w.y;
        }
    }
    __syncthreads();

    // ---- load Q fragments (B-operand): lane holds col n = 16f+lm, k = 8g+jj ----
    bf16x8 qf[4][2];
    #pragma unroll
    for (int f = 0; f < 4; ++f) {
        #pragma unroll
        for (int h = 0; h < 2; ++h) {
            bf16x8 v;
            #pragma unroll
            for (int jj = 0; jj < 8; ++jj)
                v[jj] = (short)qs[(h*32 + 8*g + jj)*LDSTRIDE + 16*f + lm];
            qf[f][h] = v;
        }
    }

    float dacc[4] = {0.f,0.f,0.f,0.f};
    float na[4]   = {0.f,0.f,0.f,0.f};
    float nb[4]   = {0.f,0.f,0.f,0.f};
    float nc[4]   = {0.f,0.f,0.f,0.f};

    const int ntiles = mchunk / 64;
    for (int tile = 0; tile < ntiles; ++tile) {
        const int m0 = mbase + tile*64;
        __syncthreads();  // previous tile's LDS reads drained before overwrite
        // ---- stage K tile: 64d x 64m ----
        {
            const float* src = ke + (size_t)b * D_ * M_ + m0 + 4*tq;
            #pragma unroll
            for (int i = 0; i < 16; ++i) {
                int d = 4*i + dg;
                float4 v = *(const float4*)(src + (size_t)d * M_);
                uint2 w = pack4(v);
                unsigned* p32 = (unsigned*)&ks[d*LDSTRIDE + 4*tq];
                p32[0] = w.x; p32[1] = w.y;
            }
        }
        // ---- stage tgt tile (f32) ----
        if (t < 48) {
            int c = t >> 4, j = t & 15;
            float4 v = *(const float4*)(tgt + (size_t)(b*3 + c)*M_ + m0 + 4*j);
            *(float4*)(ts + c*64 + 4*j) = v;
        }
        __syncthreads();

        #pragma unroll
        for (int step = 0; step < 4; ++step) {
            // A-operand: lane holds row m = step*16 + lm, k = 8g+jj (ka: d=k, kb: d=32+k)
            bf16x8 ka, kb;
            #pragma unroll
            for (int jj = 0; jj < 8; ++jj) {
                ka[jj] = (short)ks[(8*g + jj)*LDSTRIDE + step*16 + lm];
                kb[jj] = (short)ks[(32 + 8*g + jj)*LDSTRIDE + step*16 + lm];
            }

            // tgt values for this lane's 4 m-rows: m = step*16 + 4*g + r
            f32x4 tv0 = *(const f32x4*)(ts + 0*64 + step*16 + 4*g);
            f32x4 tv1 = *(const f32x4*)(ts + 1*64 + step*16 + 4*g);
            f32x4 tv2 = *(const f32x4*)(ts + 2*64 + step*16 + 4*g);

            #pragma unroll
            for (int f = 0; f < 4; ++f) {
                f32x4 c4 = {0.f,0.f,0.f,0.f};
                c4 = __builtin_amdgcn_mfma_f32_16x16x32_bf16(ka, qf[f][0], c4, 0, 0, 0);
                c4 = __builtin_amdgcn_mfma_f32_16x16x32_bf16(kb, qf[f][1], c4, 0, 0, 0);
                float e0 = exp2f(c4[0]*SCALE2);
                float e1 = exp2f(c4[1]*SCALE2);
                float e2 = exp2f(c4[2]*SCALE2);
                float e3 = exp2f(c4[3]*SCALE2);
                dacc[f] += (e0+e1)+(e2+e3);
                na[f] += e0*tv0[0] + e1*tv0[1] + e2*tv0[2] + e3*tv0[3];
                nb[f] += e0*tv1[0] + e1*tv1[1] + e2*tv1[2] + e3*tv1[3];
                nc[f] += e0*tv2[0] + e1*tv2[1] + e2*tv2[2] + e3*tv2[3];
            }
        }
    }

    // reduce across the 4 row-groups (lanes differing in bits 4,5 share col n)
    #pragma unroll
    for (int f = 0; f < 4; ++f) {
        dacc[f] += __shfl_xor(dacc[f], 16, 64); dacc[f] += __shfl_xor(dacc[f], 32, 64);
        na[f]   += __shfl_xor(na[f],   16, 64); na[f]   += __shfl_xor(na[f],   32, 64);
        nb[f]   += __shfl_xor(nb[f],   16, 64); nb[f]   += __shfl_xor(nb[f],   32, 64);
        nc[f]   += __shfl_xor(nc[f],   16, 64); nc[f]   += __shfl_xor(nc[f],   32, 64);
    }

    if (t < 16) {
        if constexpr (DIRECT) {
            #pragma unroll
            for (int f = 0; f < 4; ++f) {
                int n = n0 + 16*f + t;
                float inv = 1.0f / dacc[f];
                out[B3N + ((size_t)b*3 + 0)*N_ + n] = na[f]*inv;
                out[B3N + ((size_t)b*3 + 1)*N_ + n] = nb[f]*inv;
                out[B3N + ((size_t)b*3 + 2)*N_ + n] = nc[f]*inv;
            }
        } else {
            size_t base = ((size_t)slice*B_ + b)*4*N_;
            #pragma unroll
            for (int f = 0; f < 4; ++f) {
                int n = n0 + 16*f + t;
                ws[base + 0*N_ + n] = dacc[f];
                ws[base + 1*N_ + n] = na[f];
                ws[base + 2*N_ + n] = nb[f];
                ws[base + 3*N_ + n] = nc[f];
            }
        }
    }
}

__global__ void copy_kernel(const float4* __restrict__ src, float4* __restrict__ out) {
    int i = blockIdx.x*256 + threadIdx.x;   // grid = B3N/4/256 = 96 exactly
    out[i] = src[i];
}

template<int S>
__global__ void finalize_kernel(const float* __restrict__ ws, float* __restrict__ out) {
    int tid = blockIdx.x*256 + threadIdx.x;  // B*N threads
    int b = tid >> 12;
    int n = tid & (N_-1);
    float den = 0.f, x = 0.f, y = 0.f, z = 0.f;
    #pragma unroll
    for (int s = 0; s < S; ++s) {
        size_t base = ((size_t)s*B_ + b)*4*N_ + n;
        den += ws[base];
        x   += ws[base + 1*N_];
        y   += ws[base + 2*N_];
        z   += ws[base + 3*N_];
    }
    float inv = 1.0f/den;
    out[B3N + ((size_t)b*3 + 0)*N_ + n] = x*inv;
    out[B3N + ((size_t)b*3 + 1)*N_ + n] = y*inv;
    out[B3N + ((size_t)b*3 + 2)*N_ + n] = z*inv;
}

extern "C" void kernel_launch(void* const* d_in, const int* in_sizes, int n_in,
                              void* d_out, int out_size, void* d_ws, size_t ws_size,
                              hipStream_t stream) {
    const float* qe  = (const float*)d_in[0];   // src_embedding [B,D,N]
    const float* ke  = (const float*)d_in[1];   // tgt_embedding [B,D,M]
    const float* src = (const float*)d_in[2];   // src [B,3,N]
    const float* tg  = (const float*)d_in[3];   // tgt [B,3,M]
    float* out = (float*)d_out;
    float* ws  = (float*)d_ws;

    copy_kernel<<<96, 256, 0, stream>>>((const float4*)src, (float4*)out);

    const size_t need = (size_t)4 * B_ * 4 * N_ * sizeof(float);  // 2 MB
    if (ws_size >= need) {
        dim3 grid(N_/64, 4, B_);   // 64 x 4 x 8 = 2048 blocks
        attn_kernel<4, false><<<grid, 64, 0, stream>>>(qe, ke, tg, ws, out);
        finalize_kernel<4><<<(B_*N_)/256, 256, 0, stream>>>(ws, out);
    } else {
        dim3 grid(N_/64, 1, B_);
        attn_kernel<1, true><<<grid, 64, 0, stream>>>(qe, ke, tg, nullptr, out);
    }
}

// Round 5
// 65.099 us; speedup vs baseline: 1.3060x; 1.3060x over previous
//
#include <hip/hip_runtime.h>
#include <hip/hip_bf16.h>

#define B_ 8
#define D_ 64
#define N_ 4096
#define M_ 4096
#define B3N (B_*3*N_)

// exp(s/8) = exp2(s * 0.125 * log2(e)) ; SCALE2 folded into Q prepass
#define SCALE2 0.18033688011112042f

typedef short bf16x8 __attribute__((ext_vector_type(8)));
typedef float f32x4 __attribute__((ext_vector_type(4)));
typedef __fp16 half2v __attribute__((ext_vector_type(2)));
typedef __fp16 half4v __attribute__((ext_vector_type(4)));
typedef unsigned int uint4v __attribute__((ext_vector_type(4)));

// ---- portable wrappers -----------------------------------------------------
#if __has_builtin(__builtin_amdgcn_exp2f)
#define EXP2(x) __builtin_amdgcn_exp2f(x)
#else
#define EXP2(x) exp2f(x)
#endif

__device__ __forceinline__ unsigned fbits(float f) { return __builtin_bit_cast(unsigned, f); }

// pack two f32 -> one u32 of two bf16 (truncation) : [lo16]=lo, [hi16]=hi
__device__ __forceinline__ unsigned pkbf(float hi, float lo) {
#if __has_builtin(__builtin_amdgcn_perm)
    return __builtin_amdgcn_perm(fbits(hi), fbits(lo), 0x07060302u);
#else
    return (fbits(hi) & 0xFFFF0000u) | (fbits(lo) >> 16);
#endif
}

__device__ __forceinline__ half2v pkhalf(float a, float b) {
#if __has_builtin(__builtin_amdgcn_cvt_pkrtz)
    return __builtin_bit_cast(half2v, __builtin_amdgcn_cvt_pkrtz(a, b));   // low=a, high=b
#else
    half2v r; r[0] = (__fp16)a; r[1] = (__fp16)b; return r;
#endif
}

// legacy-shape MFMA builtin (CDNA1-era spelling: no underscore before f16).
// V4h x V4h -> V4f. Present on gfx950 (ISA: v_mfma_f32_16x16x16_f16, 2/2/4 regs).
#define MFMA_PV(a,b,c) __builtin_amdgcn_mfma_f32_16x16x16f16((a),(b),(c),0,0,0)

// ---- prepass: [b][d][p] f32 -> [b][p][d] bf16 (trunc), optional scale ------
__global__ __launch_bounds__(64) void prep_kernel(const float* __restrict__ qe,
                                                  const float* __restrict__ ke,
                                                  unsigned short* __restrict__ qb,
                                                  unsigned short* __restrict__ kb)
{
    int blk = blockIdx.x;            // 0..1023 ; >=512 -> Q with scale
    bool isq = blk >= 512;
    int l  = blk & 511;
    int b  = l >> 6;
    int p  = ((l & 63) << 6) + threadIdx.x;
    const float* ip = (isq ? qe : ke) + (size_t)b * D_ * M_ + p;
    unsigned short* op = (isq ? qb : kb) + ((size_t)b * M_ + p) * D_;
    float sc = isq ? SCALE2 : 1.0f;
    #pragma unroll
    for (int i = 0; i < 8; ++i) {
        float v[8];
        #pragma unroll
        for (int d = 0; d < 8; ++d) v[d] = ip[(size_t)(8*i + d) * M_] * sc;
        uint4v w;
        #pragma unroll
        for (int j = 0; j < 4; ++j) w[j] = pkbf(v[2*j+1], v[2*j]);
        *(uint4v*)(op + 8*i) = w;
    }
}

// ---- main attention kernel (Tier A) ----------------------------------------
// 1 wave/block, n-tile=64, no LDS, no barriers.
// QK^T: mfma_f32_16x16x32_bf16(K,Q) -> c4: row m_local=4g+r, col n=lm (verified r2).
// PV+denominator: mfma 16x16x16 f16 (A=[tgt_x,tgt_y,tgt_z,ones] rows, B=exp(c4)).
// c4 layout == 16x16x16 B-operand layout (k=4g+j, col=lm): zero shuffles.
template<int S>
__global__ __launch_bounds__(64, 4)
void attn2_kernel(const unsigned short* __restrict__ qb,
                  const unsigned short* __restrict__ kb,
                  const float* __restrict__ tgt,
                  float* __restrict__ partials)
{
    const int t  = threadIdx.x, lm = t & 15, g = t >> 4;
    const int b  = blockIdx.z, slice = blockIdx.y, n0 = blockIdx.x * 64;
    const int mchunk = M_ / S, mbase = slice * mchunk;

    // Q fragments (B-operand): lane holds col n=n0+16f+lm, k=32h+8g+jj (d-contig)
    bf16x8 qf[4][2];
    #pragma unroll
    for (int f = 0; f < 4; ++f) {
        const unsigned short* qrow = qb + ((size_t)b * N_ + n0 + 16*f + lm) * D_ + 8*g;
        qf[f][0] = *(const bf16x8*)(qrow);
        qf[f][1] = *(const bf16x8*)(qrow + 32);
    }

    const bool isones = (lm & 3) == 3;
    const int  c_ld   = isones ? 2 : (lm & 3);
    half2v one2 = pkhalf(1.0f, 1.0f);
    const half4v ones4 = __builtin_shufflevector(one2, one2, 0, 1, 0, 1);

    const unsigned short* krow = kb + ((size_t)b * M_ + mbase + lm) * D_ + 8*g;
    const float* tp = tgt + ((size_t)b * 3 + c_ld) * M_ + mbase + 4*g;

    f32x4 D2[4] = {{0,0,0,0},{0,0,0,0},{0,0,0,0},{0,0,0,0}};

    for (int ms = 0; ms < mchunk; ms += 16) {
        bf16x8 ka  = *(const bf16x8*)(krow);        // k = 8g+jj  (d 0..31 slice)
        bf16x8 kb8 = *(const bf16x8*)(krow + 32);   // k = 32+8g+jj
        f32x4 tv = *(const f32x4*)(tp);             // tgt[c][m = mbase+ms+4g+0..3]
        half2v a01 = pkhalf(tv[0], tv[1]);
        half2v a23 = pkhalf(tv[2], tv[3]);
        half4v afr = __builtin_shufflevector(a01, a23, 0, 1, 2, 3);
        afr = isones ? ones4 : afr;

        #pragma unroll
        for (int f = 0; f < 4; ++f) {
            f32x4 c4 = {0,0,0,0};
            c4 = __builtin_amdgcn_mfma_f32_16x16x32_bf16(ka,  qf[f][0], c4, 0, 0, 0);
            c4 = __builtin_amdgcn_mfma_f32_16x16x32_bf16(kb8, qf[f][1], c4, 0, 0, 0);
            float e0 = EXP2(c4[0]);
            float e1 = EXP2(c4[1]);
            float e2 = EXP2(c4[2]);
            float e3 = EXP2(c4[3]);
            half2v p01 = pkhalf(e0, e1);
            half2v p23 = pkhalf(e2, e3);
            half4v pbf = __builtin_shufflevector(p01, p23, 0, 1, 2, 3);
            D2[f] = MFMA_PV(afr, pbf, D2[f]);
        }
        krow += 16 * D_;
        tp   += 16;
    }

    // lane t<16 (g=0) holds D rows 0..3 = {x, y, z, denom} for col n=16f+t
    if (t < 16) {
        size_t base = ((size_t)slice * B_ + b) * 4 * N_;
        #pragma unroll
        for (int f = 0; f < 4; ++f) {
            int n = n0 + 16*f + t;
            partials[base + 0*N_ + n] = D2[f][3];   // denominator (ones row)
            partials[base + 1*N_ + n] = D2[f][0];   // x numerator
            partials[base + 2*N_ + n] = D2[f][1];   // y
            partials[base + 3*N_ + n] = D2[f][2];   // z
        }
    }
}

// ---- Tier B fallback: round-2 passing kernel (LDS-staged, VALU PV) ---------
#define LDSTRIDE 66
__device__ __forceinline__ unsigned short f2bf(float f) {
    union { __hip_bfloat16 h; unsigned short u; } cv;
    cv.h = __float2bfloat16(f);
    return cv.u;
}
__device__ __forceinline__ uint2 pack4(float4 v) {
    uint2 r;
    r.x = (unsigned)f2bf(v.x) | ((unsigned)f2bf(v.y) << 16);
    r.y = (unsigned)f2bf(v.z) | ((unsigned)f2bf(v.w) << 16);
    return r;
}

template<int S, bool DIRECT>
__global__ __launch_bounds__(64)
void attn_kernel(const float* __restrict__ qe, const float* __restrict__ ke,
                 const float* __restrict__ tgt, float* __restrict__ ws,
                 float* __restrict__ out)
{
    __shared__ unsigned short qs[64 * LDSTRIDE];
    __shared__ unsigned short ks[64 * LDSTRIDE];
    __shared__ __align__(16) float ts[3 * 64];

    const int t  = threadIdx.x;
    const int b  = blockIdx.z;
    const int n0 = blockIdx.x * 64;
    const int slice = blockIdx.y;
    const int mchunk = M_ / S;
    const int mbase  = slice * mchunk;
    const int tq = t & 15;
    const int dg = t >> 4;
    const int g  = dg;
    const int lm = tq;

    {
        const float* src = qe + (size_t)b * D_ * N_ + n0 + 4*tq;
        #pragma unroll
        for (int i = 0; i < 16; ++i) {
            int d = 4*i + dg;
            float4 v = *(const float4*)(src + (size_t)d * N_);
            uint2 w = pack4(v);
            unsigned* p32 = (unsigned*)&qs[d*LDSTRIDE + 4*tq];
            p32[0] = w.x; p32[1] = w.y;
        }
    }
    __syncthreads();

    bf16x8 qf[4][2];
    #pragma unroll
    for (int f = 0; f < 4; ++f) {
        #pragma unroll
        for (int h = 0; h < 2; ++h) {
            bf16x8 v;
            #pragma unroll
            for (int jj = 0; jj < 8; ++jj)
                v[jj] = (short)qs[(h*32 + 8*g + jj)*LDSTRIDE + 16*f + lm];
            qf[f][h] = v;
        }
    }

    float dacc[4] = {0.f,0.f,0.f,0.f};
    float na[4]   = {0.f,0.f,0.f,0.f};
    float nb[4]   = {0.f,0.f,0.f,0.f};
    float nc[4]   = {0.f,0.f,0.f,0.f};

    const int ntiles = mchunk / 64;
    for (int tile = 0; tile < ntiles; ++tile) {
        const int m0 = mbase + tile*64;
        __syncthreads();
        {
            const float* src = ke + (size_t)b * D_ * M_ + m0 + 4*tq;
            #pragma unroll
            for (int i = 0; i < 16; ++i) {
                int d = 4*i + dg;
                float4 v = *(const float4*)(src + (size_t)d * M_);
                uint2 w = pack4(v);
                unsigned* p32 = (unsigned*)&ks[d*LDSTRIDE + 4*tq];
                p32[0] = w.x; p32[1] = w.y;
            }
        }
        if (t < 48) {
            int c = t >> 4, j = t & 15;
            float4 v = *(const float4*)(tgt + (size_t)(b*3 + c)*M_ + m0 + 4*j);
            *(float4*)(ts + c*64 + 4*j) = v;
        }
        __syncthreads();

        #pragma unroll
        for (int step = 0; step < 4; ++step) {
            bf16x8 ka, kb;
            #pragma unroll
            for (int jj = 0; jj < 8; ++jj) {
                ka[jj] = (short)ks[(8*g + jj)*LDSTRIDE + step*16 + lm];
                kb[jj] = (short)ks[(32 + 8*g + jj)*LDSTRIDE + step*16 + lm];
            }
            f32x4 tv0 = *(const f32x4*)(ts + 0*64 + step*16 + 4*g);
            f32x4 tv1 = *(const f32x4*)(ts + 1*64 + step*16 + 4*g);
            f32x4 tv2 = *(const f32x4*)(ts + 2*64 + step*16 + 4*g);

            #pragma unroll
            for (int f = 0; f < 4; ++f) {
                f32x4 c4 = {0.f,0.f,0.f,0.f};
                c4 = __builtin_amdgcn_mfma_f32_16x16x32_bf16(ka, qf[f][0], c4, 0, 0, 0);
                c4 = __builtin_amdgcn_mfma_f32_16x16x32_bf16(kb, qf[f][1], c4, 0, 0, 0);
                float e0 = exp2f(c4[0]*SCALE2);
                float e1 = exp2f(c4[1]*SCALE2);
                float e2 = exp2f(c4[2]*SCALE2);
                float e3 = exp2f(c4[3]*SCALE2);
                dacc[f] += (e0+e1)+(e2+e3);
                na[f] += e0*tv0[0] + e1*tv0[1] + e2*tv0[2] + e3*tv0[3];
                nb[f] += e0*tv1[0] + e1*tv1[1] + e2*tv1[2] + e3*tv1[3];
                nc[f] += e0*tv2[0] + e1*tv2[1] + e2*tv2[2] + e3*tv2[3];
            }
        }
    }

    #pragma unroll
    for (int f = 0; f < 4; ++f) {
        dacc[f] += __shfl_xor(dacc[f], 16, 64); dacc[f] += __shfl_xor(dacc[f], 32, 64);
        na[f]   += __shfl_xor(na[f],   16, 64); na[f]   += __shfl_xor(na[f],   32, 64);
        nb[f]   += __shfl_xor(nb[f],   16, 64); nb[f]   += __shfl_xor(nb[f],   32, 64);
        nc[f]   += __shfl_xor(nc[f],   16, 64); nc[f]   += __shfl_xor(nc[f],   32, 64);
    }

    if (t < 16) {
        if constexpr (DIRECT) {
            #pragma unroll
            for (int f = 0; f < 4; ++f) {
                int n = n0 + 16*f + t;
                float inv = 1.0f / dacc[f];
                out[B3N + ((size_t)b*3 + 0)*N_ + n] = na[f]*inv;
                out[B3N + ((size_t)b*3 + 1)*N_ + n] = nb[f]*inv;
                out[B3N + ((size_t)b*3 + 2)*N_ + n] = nc[f]*inv;
            }
        } else {
            size_t base = ((size_t)slice*B_ + b)*4*N_;
            #pragma unroll
            for (int f = 0; f < 4; ++f) {
                int n = n0 + 16*f + t;
                ws[base + 0*N_ + n] = dacc[f];
                ws[base + 1*N_ + n] = na[f];
                ws[base + 2*N_ + n] = nb[f];
                ws[base + 3*N_ + n] = nc[f];
            }
        }
    }
}

// ---- shared epilogue kernels ------------------------------------------------
__global__ void copy_kernel(const float4* __restrict__ src, float4* __restrict__ out) {
    int i = blockIdx.x*256 + threadIdx.x;   // grid = B3N/4/256 = 96 exactly
    out[i] = src[i];
}

template<int S>
__global__ void finalize_kernel(const float* __restrict__ ws, float* __restrict__ out) {
    int tid = blockIdx.x*256 + threadIdx.x;  // B*N threads
    int b = tid >> 12;
    int n = tid & (N_-1);
    float den = 0.f, x = 0.f, y = 0.f, z = 0.f;
    #pragma unroll
    for (int s = 0; s < S; ++s) {
        size_t base = ((size_t)s*B_ + b)*4*N_ + n;
        den += ws[base];
        x   += ws[base + 1*N_];
        y   += ws[base + 2*N_];
        z   += ws[base + 3*N_];
    }
    float inv = 1.0f/den;
    out[B3N + ((size_t)b*3 + 0)*N_ + n] = x*inv;
    out[B3N + ((size_t)b*3 + 1)*N_ + n] = y*inv;
    out[B3N + ((size_t)b*3 + 2)*N_ + n] = z*inv;
}

extern "C" void kernel_launch(void* const* d_in, const int* in_sizes, int n_in,
                              void* d_out, int out_size, void* d_ws, size_t ws_size,
                              hipStream_t stream) {
    const float* qe  = (const float*)d_in[0];   // src_embedding [B,D,N]
    const float* ke  = (const float*)d_in[1];   // tgt_embedding [B,D,M]
    const float* src = (const float*)d_in[2];   // src [B,3,N]
    const float* tg  = (const float*)d_in[3];   // tgt [B,3,M]
    float* out = (float*)d_out;

    copy_kernel<<<96, 256, 0, stream>>>((const float4*)src, (float4*)out);

    const size_t embElems  = (size_t)B_ * M_ * D_;              // 2M bf16 each
    const size_t needA = 2 * embElems * 2 + (size_t)8 * B_ * 4 * N_ * 4;  // 12 MB
    const size_t needB = (size_t)4 * B_ * 4 * N_ * sizeof(float);         // 2 MB

    if (ws_size >= needA) {
        unsigned short* kb16 = (unsigned short*)d_ws;
        unsigned short* qb16 = kb16 + embElems;
        float* partials = (float*)((char*)d_ws + 2 * embElems * 2);
        prep_kernel<<<1024, 64, 0, stream>>>(qe, ke, qb16, kb16);
        dim3 grid(N_/64, 8, B_);   // 4096 one-wave blocks = 16 waves/CU
        attn2_kernel<8><<<grid, 64, 0, stream>>>(qb16, kb16, tg, partials);
        finalize_kernel<8><<<(B_*N_)/256, 256, 0, stream>>>(partials, out);
    } else if (ws_size >= needB) {
        float* ws = (float*)d_ws;
        dim3 grid(N_/64, 4, B_);
        attn_kernel<4, false><<<grid, 64, 0, stream>>>(qe, ke, tg, ws, out);
        finalize_kernel<4><<<(B_*N_)/256, 256, 0, stream>>>(ws, out);
    } else {
        dim3 grid(N_/64, 1, B_);
        attn_kernel<1, true><<<grid, 64, 0, stream>>>(qe, ke, tg, nullptr, out);
    }
}